// Round 1
// baseline (16927.885 us; speedup 1.0000x reference)
//
#include <hip/hip_runtime.h>
#include <math.h>

#define H   512
#define B   512
#define T   512
#define TGT 28

typedef __bf16 bf16x8 __attribute__((ext_vector_type(8)));
typedef float  f32x4  __attribute__((ext_vector_type(4)));
typedef unsigned short u16;

// ws byte offsets (layout unchanged from previous version)
#define OFF_WPH  0x000000u  // Wpack_hi 2MB (frag-linear bf16)
#define OFF_WPL  0x200000u  // Wpack_lo 2MB
#define OFF_HHI0 0x400000u  // 512KB h hi buf0   (zeroed)
#define OFF_HLO0 0x480000u  // 512KB h lo buf0   (zeroed)
#define OFF_SYNC 0x500000u  // 4KB   sync page   (zeroed): [0..255] slot ctrs, [256..511] flags
#define OFF_HHI1 0x501000u  // 512KB h hi buf1
#define OFF_HLO1 0x581000u  // 512KB h lo buf1

// LDS: W hi 64KB + W lo 64KB + gates[64][68] f32 (17408B) = 148480B -> 1 WG/CU
#define SMEM_BYTES (131072 + 64 * 68 * 4)

__device__ inline u16 f2bf(float x) {
    unsigned u = __builtin_bit_cast(unsigned, x);
    u += 0x7FFFu + ((u >> 16) & 1u);          // RNE
    return (u16)(u >> 16);
}
__device__ inline float bf2f(u16 h) {
    unsigned u = ((unsigned)h) << 16;
    return __builtin_bit_cast(float, u);
}
// fast activations: v_exp_f32 + v_rcp_f32 (~1e-7 rel err, far below bf16 hi/lo noise)
__device__ inline float fsig(float x) {
    return __builtin_amdgcn_rcpf(1.0f + __expf(-x));
}
__device__ inline float ftanh(float x) {
    float s = __builtin_amdgcn_rcpf(1.0f + __expf(-2.0f * x));
    return fmaf(2.0f, s, -1.0f);
}

// ---------------------------------------------------------------------------
// Pack W_hh frag-linear bf16 hi/lo.  idx: r(5)|q(2)|S(4)|l(6), 8 k each.
// g = q*512 + r*16 + (l&15) ; k = S*32 + (l>>4)*8
// ---------------------------------------------------------------------------
__global__ __launch_bounds__(256) void init_pack(const float* __restrict__ Whh,
                                                 u16* __restrict__ wph,
                                                 u16* __restrict__ wpl) {
    int idx = blockIdx.x * 256 + threadIdx.x;   // [0, 131072)
    int l  = idx & 63;
    int S  = (idx >> 6) & 15;
    int q  = (idx >> 10) & 3;
    int r  = idx >> 12;
    int g  = q * 512 + r * 16 + (l & 15);
    int k  = S * 32 + ((l >> 4) * 8);
    const float* src = Whh + (size_t)g * H + k;
    __align__(16) u16 hi8[8];
    __align__(16) u16 lo8[8];
#pragma unroll
    for (int j = 0; j < 8; ++j) {
        float w = src[j];
        u16 hb = f2bf(w);
        hi8[j] = hb;
        lo8[j] = f2bf(w - bf2f(hb));
    }
    *(uint4*)(wph + (size_t)idx * 8) = *(const uint4*)hi8;
    *(uint4*)(wpl + (size_t)idx * 8) = *(const uint4*)lo8;
}

// zero [OFF_HHI0, OFF_HHI1) = h buf0 hi/lo + sync page = 263168 dwords
__global__ __launch_bounds__(256) void init_state(unsigned* __restrict__ zbase) {
    int idx = blockIdx.x * 256 + threadIdx.x;
    if (idx < 263168) zbase[idx] = 0u;
}

// ---------------------------------------------------------------------------
// Persistent XCD-local LSTM, dataflow-synchronized (no central barrier).
// 256 WGs x 512 thr, cooperative, 1 WG/CU. XCD p owns batch rows [p*64,+64).
// Worker r (0..31) owns gate-cols {q*512 + r*16 .. +16}; W slice in LDS.
// Wave w: rg = w&1 (32-row half), kh = w>>1 (K-quarter, 128 k).
//
// Per step:
//   [sv prefetch] -> [flag wait: 8 producers of my K-quarter done step t-1]
//   -> buffer_inv -> MFMA (unchanged) -> kh0 writes partials / SYNC1
//   -> kh1..3 concurrent ds_add_f32 / SYNC2 -> cell update (all waves,
//   2 cells/thread, fast act) -> h store -> vmcnt(0) -> flag += 1 (per wave).
//
// flags[p*32+r] at sync[256+..]: 8 adds/CU/step => value 8*(t+1) when CU r
// finished step t. Consumer wave of K-quarter kh waits flags[kh*8 + 0..7] >= 8t.
// kh0 additionally waits own flag >= 8t just before overwriting gates LDS
// (all 8 own waves' gate reads of step t-1 done).
// Safety: 2-buffer h + flag transitivity orders every h_{t-1} read before any
// h_{t+1} overwrite; release = vmcnt(0) (write-through L1 -> local L2);
// acquire = buffer_inv sc0 after flag observed.
// ---------------------------------------------------------------------------
__global__ __launch_bounds__(512, 1) void lstm_persistent(
    const u16* __restrict__ wph, const u16* __restrict__ wpl,
    u16* __restrict__ hhi0, u16* __restrict__ hlo0,
    u16* __restrict__ hhi1, u16* __restrict__ hlo1,
    int* __restrict__ sync, const float* __restrict__ seq,
    const float* __restrict__ Wih, const float* __restrict__ bih,
    const float* __restrict__ bhh)
{
    extern __shared__ char smem[];
    u16* wh = (u16*)smem;                         // 64KB
    u16* wl = wh + 32768;                         // 64KB
    float (*gates)[68] = (float(*)[68])(smem + 131072);

    const int tid  = threadIdx.x;
    const int l    = tid & 63;
    const int wave = tid >> 6;
    const int mt   = wave & 1;                    // 32-row half
    const int kh   = wave >> 1;                   // K-quarter 0..3

    // ---- partition assignment: physical XCD id + per-XCD slot ----
    __shared__ int sh_pr[2];
    if (tid == 0) {
        unsigned xcc;
        asm volatile("s_getreg_b32 %0, hwreg(HW_REG_XCC_ID)" : "=s"(xcc));
        int p = (int)(xcc & 7u);
        int r = __hip_atomic_fetch_add(&sync[p * 32], 1,
                                       __ATOMIC_RELAXED, __HIP_MEMORY_SCOPE_AGENT);
        sh_pr[0] = p;
        sh_pr[1] = r;                             // 0..31 (pigeonhole: 1 WG/CU)
    }
    __syncthreads();
    const int p = sh_pr[0];
    const int r = sh_pr[1];
    int* flags = &sync[256 + p * 32];             // 32 per-CU progress flags

    // ---- stage W slice (worker r) into LDS, once ----
    {
        const uint4* gh = (const uint4*)(wph + (size_t)r * 32768);
        const uint4* gl = (const uint4*)(wpl + (size_t)r * 32768);
        uint4* sh = (uint4*)wh;
        uint4* sl = (uint4*)wl;
#pragma unroll
        for (int i = 0; i < 8; ++i) {
            int idx = tid + i * 512;              // 0..4095
            sh[idx] = gh[idx];
            sl[idx] = gl[idx];
        }
    }

    // ---- thread-resident cell constants ----
    const int cc   = tid & 15;
    const int m0   = tid >> 4;                    // 0..31
    const int kcol = r * 16 + cc;
    float wib[4], bb[4];
#pragma unroll
    for (int q = 0; q < 4; ++q) {
        int g = q * 512 + kcol;
        wib[q] = Wih[g];
        bb[q]  = bih[g] + bhh[g];
    }
    float cr0 = 0.0f, cr1 = 0.0f;
    const int pb = p * 64;                        // partition batch base
    const int b0 = pb + m0;
    const int b1 = b0 + 32;

    const int arow0 = (pb + mt * 32 + (l & 15)) * H;
    const int arow1 = arow0 + 16 * H;

    // my K-quarter's producers: CUs kh*8 .. kh*8+7
    const int fi = kh * 8 + (l & 7);

    __syncthreads();                              // W staged

    for (int t = 0; t < T; ++t) {
        const u16* hih = (t & 1) ? hhi1 : hhi0;
        const u16* hil = (t & 1) ? hlo1 : hlo0;
        u16* hoh = (t & 1) ? hhi0 : hhi1;
        u16* hol = (t & 1) ? hlo0 : hlo1;

        // prefetch seq early: hides L2 latency under the flag wait / MFMA
        float sv0 = seq[(size_t)b0 * T + t];
        float sv1 = seq[(size_t)b1 * T + t];

        // ---- dataflow wait: my K-quarter's producers finished step t-1 ----
        {
            const int tgt = 8 * t;
            for (;;) {
                int v = __hip_atomic_load(&flags[fi], __ATOMIC_RELAXED,
                                          __HIP_MEMORY_SCOPE_AGENT);
                if (__all(v >= tgt)) break;
                __builtin_amdgcn_s_sleep(1);
            }
        }
        asm volatile("buffer_inv sc0" ::: "memory");      // acquire: drop L1

        f32x4 acc[2][4] = {};

#pragma unroll
        for (int s = 0; s < 4; ++s) {
            const int S  = kh * 4 + s;
            const int ka = S * 32 + ((l >> 4) * 8);
            bf16x8 a0h = *(const bf16x8*)(hih + arow0 + ka);
            bf16x8 a1h = *(const bf16x8*)(hih + arow1 + ka);
            bf16x8 a0l = *(const bf16x8*)(hil + arow0 + ka);
            bf16x8 a1l = *(const bf16x8*)(hil + arow1 + ka);
#pragma unroll
            for (int n = 0; n < 4; ++n) {
                const int fo = ((n * 16 + S) * 64 + l) * 8;
                bf16x8 bh = *(const bf16x8*)(wh + fo);
                bf16x8 bl = *(const bf16x8*)(wl + fo);
                acc[0][n] = __builtin_amdgcn_mfma_f32_16x16x32_bf16(a0h, bh, acc[0][n], 0, 0, 0);
                acc[1][n] = __builtin_amdgcn_mfma_f32_16x16x32_bf16(a1h, bh, acc[1][n], 0, 0, 0);
                acc[0][n] = __builtin_amdgcn_mfma_f32_16x16x32_bf16(a0h, bl, acc[0][n], 0, 0, 0);
                acc[1][n] = __builtin_amdgcn_mfma_f32_16x16x32_bf16(a1h, bl, acc[1][n], 0, 0, 0);
                acc[0][n] = __builtin_amdgcn_mfma_f32_16x16x32_bf16(a0l, bh, acc[0][n], 0, 0, 0);
                acc[1][n] = __builtin_amdgcn_mfma_f32_16x16x32_bf16(a1l, bh, acc[1][n], 0, 0, 0);
            }
        }

        // ---- K reduction: kh0 writes, kh1..3 add concurrently (ds_add_f32) ----
        // D: col=lane&15, row=(lane>>4)*4+reg
        if (kh == 0) {
            // gates-buffer protect: all 8 own waves read step t-1's gates before
            // overwrite (own flag == 8t once own CU finished step t-1)
            const int tgt = 8 * t;
            for (;;) {
                int v = __hip_atomic_load(&flags[r], __ATOMIC_RELAXED,
                                          __HIP_MEMORY_SCOPE_AGENT);
                if (v >= tgt) break;
                __builtin_amdgcn_s_sleep(1);
            }
#pragma unroll
            for (int ms = 0; ms < 2; ++ms)
#pragma unroll
                for (int n = 0; n < 4; ++n)
#pragma unroll
                    for (int reg = 0; reg < 4; ++reg) {
                        int m  = mt * 32 + ms * 16 + (l >> 4) * 4 + reg;
                        int n2 = n * 16 + (l & 15);
                        gates[m][n2] = acc[ms][n][reg];
                    }
        }
        __syncthreads();                          // SYNC1: partials written
        if (kh != 0) {
#pragma unroll
            for (int ms = 0; ms < 2; ++ms)
#pragma unroll
                for (int n = 0; n < 4; ++n)
#pragma unroll
                    for (int reg = 0; reg < 4; ++reg) {
                        int m  = mt * 32 + ms * 16 + (l >> 4) * 4 + reg;
                        int n2 = n * 16 + (l & 15);
                        __hip_atomic_fetch_add(&gates[m][n2], acc[ms][n][reg],
                                               __ATOMIC_RELAXED,
                                               __HIP_MEMORY_SCOPE_WORKGROUP);
                    }
        }
        __syncthreads();                          // SYNC2: gates complete

        // ---- cell update: 2 cells/thread, c in registers, fast act ----
        {
            float pre[4];
#pragma unroll
            for (int q = 0; q < 4; ++q) pre[q] = gates[m0][q * 16 + cc] + fmaf(sv0, wib[q], bb[q]);
            float ig = fsig(pre[0]);
            float fg = fsig(pre[1]);
            float gg = ftanh(pre[2]);
            float og = fsig(pre[3]);
            cr0 = fg * cr0 + ig * gg;
            float hv = og * ftanh(cr0);
            u16 hb = f2bf(hv);
            size_t ci = (size_t)b0 * H + kcol;
            hoh[ci] = hb;
            hol[ci] = f2bf(hv - bf2f(hb));
        }
        {
            float pre[4];
#pragma unroll
            for (int q = 0; q < 4; ++q) pre[q] = gates[m0 + 32][q * 16 + cc] + fmaf(sv1, wib[q], bb[q]);
            float ig = fsig(pre[0]);
            float fg = fsig(pre[1]);
            float gg = ftanh(pre[2]);
            float og = fsig(pre[3]);
            cr1 = fg * cr1 + ig * gg;
            float hv = og * ftanh(cr1);
            u16 hb = f2bf(hv);
            size_t ci = (size_t)b1 * H + kcol;
            hoh[ci] = hb;
            hol[ci] = f2bf(hv - bf2f(hb));
        }

        // ---- release: h stores drained to local L2, then bump progress flag ----
        asm volatile("s_waitcnt vmcnt(0)" ::: "memory");
        if (l == 0)
            __hip_atomic_fetch_add(&flags[r], 1, __ATOMIC_RELAXED,
                                   __HIP_MEMORY_SCOPE_AGENT);
    }
}

// ---------------------------------------------------------------------------
// MLP head
// ---------------------------------------------------------------------------
__global__ __launch_bounds__(256) void head_kernel(const u16* __restrict__ hhi,
                                                   const u16* __restrict__ hlo,
                                                   const float* __restrict__ fc1w,
                                                   const float* __restrict__ fc1b,
                                                   const float* __restrict__ fc2w,
                                                   const float* __restrict__ fc2b,
                                                   float* __restrict__ out) {
    const int b = blockIdx.x;
    const int tid = threadIdx.x;
    __shared__ __align__(16) float hb[H];
    __shared__ float z[256];

    hb[tid]       = bf2f(hhi[(size_t)b * H + tid])       + bf2f(hlo[(size_t)b * H + tid]);
    hb[tid + 256] = bf2f(hhi[(size_t)b * H + tid + 256]) + bf2f(hlo[(size_t)b * H + tid + 256]);
    __syncthreads();

    float acc = fc1b[tid];
    const float4* wr = (const float4*)(fc1w + (size_t)tid * H);
    const float4* hr = (const float4*)hb;
#pragma unroll 4
    for (int kk = 0; kk < H / 4; ++kk) {
        float4 wv = wr[kk], hv = hr[kk];
        acc += wv.x * hv.x + wv.y * hv.y + wv.z * hv.z + wv.w * hv.w;
    }
    z[tid] = fmaxf(acc, 0.0f);
    __syncthreads();

    if (tid < TGT) {
        float a = fc2b[tid];
        const float* w2 = fc2w + (size_t)tid * 256;
#pragma unroll 8
        for (int j = 0; j < 256; ++j) a += z[j] * w2[j];
        out[(size_t)b * TGT + tid] = a;
    }
}

extern "C" void kernel_launch(void* const* d_in, const int* in_sizes, int n_in,
                              void* d_out, int out_size, void* d_ws, size_t ws_size,
                              hipStream_t stream) {
    const float* seq  = (const float*)d_in[0];
    const float* Wih  = (const float*)d_in[1];
    const float* Whh  = (const float*)d_in[2];
    const float* bih  = (const float*)d_in[3];
    const float* bhh  = (const float*)d_in[4];
    const float* fc1w = (const float*)d_in[5];
    const float* fc1b = (const float*)d_in[6];
    const float* fc2w = (const float*)d_in[7];
    const float* fc2b = (const float*)d_in[8];
    float* out = (float*)d_out;

    char* wsb = (char*)d_ws;
    u16* wph  = (u16*)(wsb + OFF_WPH);
    u16* wpl  = (u16*)(wsb + OFF_WPL);
    u16* hhi0 = (u16*)(wsb + OFF_HHI0);
    u16* hlo0 = (u16*)(wsb + OFF_HLO0);
    u16* hhi1 = (u16*)(wsb + OFF_HHI1);
    u16* hlo1 = (u16*)(wsb + OFF_HLO1);
    int* sync = (int*)(wsb + OFF_SYNC);

    init_pack<<<512, 256, 0, stream>>>(Whh, wph, wpl);
    init_state<<<1028, 256, 0, stream>>>((unsigned*)(wsb + OFF_HHI0));

    hipFuncSetAttribute((const void*)lstm_persistent,
                        hipFuncAttributeMaxDynamicSharedMemorySize, SMEM_BYTES);

    void* args[] = {(void*)&wph, (void*)&wpl, (void*)&hhi0, (void*)&hlo0,
                    (void*)&hhi1, (void*)&hlo1, (void*)&sync, (void*)&seq,
                    (void*)&Wih, (void*)&bih, (void*)&bhh};
    hipLaunchCooperativeKernel((const void*)lstm_persistent, dim3(256), dim3(512),
                               args, SMEM_BYTES, stream);

    // T even -> final h in buffer 0
    head_kernel<<<B, 256, 0, stream>>>(hhi0, hlo0, fc1w, fc1b, fc2w, fc2b, out);
}

// Round 2
// 10730.399 us; speedup vs baseline: 1.5776x; 1.5776x over previous
//
#include <hip/hip_runtime.h>
#include <math.h>

#define H   512
#define B   512
#define T   512
#define TGT 28

typedef __bf16 bf16x8 __attribute__((ext_vector_type(8)));
typedef float  f32x4  __attribute__((ext_vector_type(4)));
typedef unsigned short u16;

// ws byte offsets (layout unchanged)
#define OFF_WPH  0x000000u  // Wpack_hi 2MB (frag-linear bf16)
#define OFF_WPL  0x200000u  // Wpack_lo 2MB
#define OFF_HHI0 0x400000u  // 512KB h hi buf0   (zeroed)
#define OFF_HLO0 0x480000u  // 512KB h lo buf0   (zeroed)
#define OFF_SYNC 0x500000u  // 4KB   sync page   (zeroed)
#define OFF_HHI1 0x501000u  // 512KB h hi buf1
#define OFF_HLO1 0x581000u  // 512KB h lo buf1

// LDS now holds only gates[64][68] f32 (17408B). Pad allocation to 96KB so at
// most ONE workgroup fits per CU (160KB pool) — the per-XCD slot assignment
// (r in 0..31) relies on exactly 32 WGs per XCD, which 1 WG/CU guarantees.
#define SMEM_BYTES 98304

__device__ inline u16 f2bf(float x) {
    unsigned u = __builtin_bit_cast(unsigned, x);
    u += 0x7FFFu + ((u >> 16) & 1u);          // RNE
    return (u16)(u >> 16);
}
__device__ inline float bf2f(u16 h) {
    unsigned u = ((unsigned)h) << 16;
    return __builtin_bit_cast(float, u);
}
// fast activations: v_exp_f32 + v_rcp_f32 with one Newton step (~1e-7 rel err,
// far below the bf16 hi/lo representation noise)
__device__ inline float frcp(float x) {
    float r = __builtin_amdgcn_rcpf(x);
    return r * fmaf(-x, r, 2.0f);             // NR refine
}
__device__ inline float fsig(float x) {
    return frcp(1.0f + __expf(-x));
}
__device__ inline float ftanh(float x) {
    return fmaf(2.0f, fsig(2.0f * x), -1.0f);
}

// ---------------------------------------------------------------------------
// Pack W_hh frag-linear bf16 hi/lo.  idx: r(5)|q(2)|S(4)|l(6), 8 k each.
// g = q*512 + r*16 + (l&15) ; k = S*32 + (l>>4)*8
// ---------------------------------------------------------------------------
__global__ __launch_bounds__(256) void init_pack(const float* __restrict__ Whh,
                                                 u16* __restrict__ wph,
                                                 u16* __restrict__ wpl) {
    int idx = blockIdx.x * 256 + threadIdx.x;   // [0, 131072)
    int l  = idx & 63;
    int S  = (idx >> 6) & 15;
    int q  = (idx >> 10) & 3;
    int r  = idx >> 12;
    int g  = q * 512 + r * 16 + (l & 15);
    int k  = S * 32 + ((l >> 4) * 8);
    const float* src = Whh + (size_t)g * H + k;
    __align__(16) u16 hi8[8];
    __align__(16) u16 lo8[8];
#pragma unroll
    for (int j = 0; j < 8; ++j) {
        float w = src[j];
        u16 hb = f2bf(w);
        hi8[j] = hb;
        lo8[j] = f2bf(w - bf2f(hb));
    }
    *(uint4*)(wph + (size_t)idx * 8) = *(const uint4*)hi8;
    *(uint4*)(wpl + (size_t)idx * 8) = *(const uint4*)lo8;
}

// zero [OFF_HHI0, OFF_HHI1) = h buf0 hi/lo + sync page = 263168 dwords
__global__ __launch_bounds__(256) void init_state(unsigned* __restrict__ zbase) {
    int idx = blockIdx.x * 256 + threadIdx.x;
    if (idx < 263168) zbase[idx] = 0u;
}

// ---------------------------------------------------------------------------
// Persistent XCD-local LSTM. 256 WGs x 512 thr, cooperative, 1 WG/CU.
// XCD p owns batch rows [p*64, p*64+64). Worker r (0..31) owns gate-cols
// {q*512 + r*16 .. +16}. W slice lives in REGISTERS (32 x bf16x8 per lane,
// loop-invariant). Cross-CU h exchange through the XCD's own L2 with the
// proven central barrier: ONE scalar poller per CU (tid 0), s_sleep spin.
//   release: s_waitcnt vmcnt(0) (write-through L1 -> stores in local L2)
//   arrive/spin: relaxed agent atomics by tid0 only
//   acquire: buffer_inv sc0 (L1-only invalidate)
// K-reduction: kh0 stores partials, 1 barrier, kh1..3 ds_add_f32 concurrently,
// 1 barrier (replaces 4 serialized rounds).
// ---------------------------------------------------------------------------
__global__ __launch_bounds__(512, 1) void lstm_persistent(
    const u16* __restrict__ wph, const u16* __restrict__ wpl,
    u16* __restrict__ hhi0, u16* __restrict__ hlo0,
    u16* __restrict__ hhi1, u16* __restrict__ hlo1,
    int* __restrict__ sync, const float* __restrict__ seq,
    const float* __restrict__ Wih, const float* __restrict__ bih,
    const float* __restrict__ bhh)
{
    extern __shared__ char smem[];
    float (*gates)[68] = (float(*)[68])smem;

    const int tid  = threadIdx.x;
    const int l    = tid & 63;
    const int wave = tid >> 6;
    const int mt   = wave & 1;                    // 32-row half
    const int kh   = wave >> 1;                   // K-quarter 0..3

    // ---- partition assignment: physical XCD id + per-XCD slot ----
    __shared__ int sh_pr[2];
    if (tid == 0) {
        unsigned xcc;
        asm volatile("s_getreg_b32 %0, hwreg(HW_REG_XCC_ID)" : "=s"(xcc));
        int p = (int)(xcc & 7u);
        int r = __hip_atomic_fetch_add(&sync[p * 32], 1,
                                       __ATOMIC_RELAXED, __HIP_MEMORY_SCOPE_AGENT);
        sh_pr[0] = p;
        sh_pr[1] = r;                             // 0..31 (pigeonhole: 1 WG/CU)
    }
    __syncthreads();
    const int p = sh_pr[0];
    const int r = sh_pr[1];
    int* arrp = &sync[256 + p * 32];              // arrival counter, own line

    // ---- W slice into REGISTERS, once (loop-invariant, static indices) ----
    bf16x8 wbh[16], wbl[16];
    {
        const u16* gh = wph + (size_t)r * 32768;
        const u16* gl = wpl + (size_t)r * 32768;
#pragma unroll
        for (int s = 0; s < 4; ++s)
#pragma unroll
            for (int n = 0; n < 4; ++n) {
                const int fo = ((n * 16 + (kh * 4 + s)) * 64 + l) * 8;
                wbh[s * 4 + n] = *(const bf16x8*)(gh + fo);
                wbl[s * 4 + n] = *(const bf16x8*)(gl + fo);
            }
    }

    // ---- thread-resident cell constants ----
    const int cc   = tid & 15;
    const int m0   = tid >> 4;                    // 0..31
    const int kcol = r * 16 + cc;
    float wib[4], bb[4];
#pragma unroll
    for (int q = 0; q < 4; ++q) {
        int g = q * 512 + kcol;
        wib[q] = Wih[g];
        bb[q]  = bih[g] + bhh[g];
    }
    float cr0 = 0.0f, cr1 = 0.0f;
    const int pb = p * 64;                        // partition batch base
    const int b0 = pb + m0;
    const int b1 = b0 + 32;

    const int arow0 = (pb + mt * 32 + (l & 15)) * H;
    const int arow1 = arow0 + 16 * H;

    for (int t = 0; t < T; ++t) {
        const u16* hih = (t & 1) ? hhi1 : hhi0;
        const u16* hil = (t & 1) ? hlo1 : hlo0;
        u16* hoh = (t & 1) ? hhi0 : hhi1;
        u16* hol = (t & 1) ? hlo0 : hlo1;

        // prefetch seq early: L2 latency hides under MFMA + reduction
        float sv0 = seq[(size_t)b0 * T + t];
        float sv1 = seq[(size_t)b1 * T + t];

        f32x4 acc[2][4] = {};

#pragma unroll
        for (int s = 0; s < 4; ++s) {
            const int S  = kh * 4 + s;
            const int ka = S * 32 + ((l >> 4) * 8);
            bf16x8 a0h = *(const bf16x8*)(hih + arow0 + ka);
            bf16x8 a1h = *(const bf16x8*)(hih + arow1 + ka);
            bf16x8 a0l = *(const bf16x8*)(hil + arow0 + ka);
            bf16x8 a1l = *(const bf16x8*)(hil + arow1 + ka);
#pragma unroll
            for (int n = 0; n < 4; ++n) {
                bf16x8 bh = wbh[s * 4 + n];
                bf16x8 bl = wbl[s * 4 + n];
                acc[0][n] = __builtin_amdgcn_mfma_f32_16x16x32_bf16(a0h, bh, acc[0][n], 0, 0, 0);
                acc[1][n] = __builtin_amdgcn_mfma_f32_16x16x32_bf16(a1h, bh, acc[1][n], 0, 0, 0);
                acc[0][n] = __builtin_amdgcn_mfma_f32_16x16x32_bf16(a0h, bl, acc[0][n], 0, 0, 0);
                acc[1][n] = __builtin_amdgcn_mfma_f32_16x16x32_bf16(a1h, bl, acc[1][n], 0, 0, 0);
                acc[0][n] = __builtin_amdgcn_mfma_f32_16x16x32_bf16(a0l, bh, acc[0][n], 0, 0, 0);
                acc[1][n] = __builtin_amdgcn_mfma_f32_16x16x32_bf16(a1l, bh, acc[1][n], 0, 0, 0);
            }
        }

        // ---- K reduction: kh0 stores, then kh1..3 add concurrently ----
        // D layout: col=lane&15, row=(lane>>4)*4+reg
        // (previous step's gate READS are ordered before these writes by the
        //  barrier-block __syncthreads at the end of step t-1)
        if (kh == 0) {
#pragma unroll
            for (int ms = 0; ms < 2; ++ms)
#pragma unroll
                for (int n = 0; n < 4; ++n)
#pragma unroll
                    for (int reg = 0; reg < 4; ++reg) {
                        int m  = mt * 32 + ms * 16 + (l >> 4) * 4 + reg;
                        int n2 = n * 16 + (l & 15);
                        gates[m][n2] = acc[ms][n][reg];
                    }
        }
        __syncthreads();                          // SYNC1: partials stored
        if (kh != 0) {
#pragma unroll
            for (int ms = 0; ms < 2; ++ms)
#pragma unroll
                for (int n = 0; n < 4; ++n)
#pragma unroll
                    for (int reg = 0; reg < 4; ++reg) {
                        int m  = mt * 32 + ms * 16 + (l >> 4) * 4 + reg;
                        int n2 = n * 16 + (l & 15);
                        atomicAdd(&gates[m][n2], acc[ms][n][reg]);
                    }
        }
        __syncthreads();                          // SYNC2: gates complete

        // ---- cell update: 2 cells/thread, c in registers, fast act ----
        {
            float pre[4];
#pragma unroll
            for (int q = 0; q < 4; ++q) pre[q] = gates[m0][q * 16 + cc] + fmaf(sv0, wib[q], bb[q]);
            float ig = fsig(pre[0]);
            float fg = fsig(pre[1]);
            float gg = ftanh(pre[2]);
            float og = fsig(pre[3]);
            cr0 = fg * cr0 + ig * gg;
            float hv = og * ftanh(cr0);
            u16 hb = f2bf(hv);
            size_t ci = (size_t)b0 * H + kcol;
            hoh[ci] = hb;
            hol[ci] = f2bf(hv - bf2f(hb));
        }
        {
            float pre[4];
#pragma unroll
            for (int q = 0; q < 4; ++q) pre[q] = gates[m0 + 32][q * 16 + cc] + fmaf(sv1, wib[q], bb[q]);
            float ig = fsig(pre[0]);
            float fg = fsig(pre[1]);
            float gg = ftanh(pre[2]);
            float og = fsig(pre[3]);
            cr1 = fg * cr1 + ig * gg;
            float hv = og * ftanh(cr1);
            u16 hb = f2bf(hv);
            size_t ci = (size_t)b1 * H + kcol;
            hoh[ci] = hb;
            hol[ci] = f2bf(hv - bf2f(hb));
        }

        // ---- XCD-local central barrier (skip after last step) ----
        if (t < T - 1) {
            asm volatile("s_waitcnt vmcnt(0)" ::: "memory");  // h stores in local L2
            __syncthreads();
            if (tid == 0) {
                __hip_atomic_fetch_add(arrp, 1, __ATOMIC_RELAXED,
                                       __HIP_MEMORY_SCOPE_AGENT);
                int target = 32 * (t + 1);
                while (__hip_atomic_load(arrp, __ATOMIC_RELAXED,
                                         __HIP_MEMORY_SCOPE_AGENT) < target)
                    __builtin_amdgcn_s_sleep(1);
            }
            __syncthreads();
            asm volatile("buffer_inv sc0" ::: "memory");      // invalidate L1 only
        }
    }
}

// ---------------------------------------------------------------------------
// MLP head
// ---------------------------------------------------------------------------
__global__ __launch_bounds__(256) void head_kernel(const u16* __restrict__ hhi,
                                                   const u16* __restrict__ hlo,
                                                   const float* __restrict__ fc1w,
                                                   const float* __restrict__ fc1b,
                                                   const float* __restrict__ fc2w,
                                                   const float* __restrict__ fc2b,
                                                   float* __restrict__ out) {
    const int b = blockIdx.x;
    const int tid = threadIdx.x;
    __shared__ __align__(16) float hb[H];
    __shared__ float z[256];

    hb[tid]       = bf2f(hhi[(size_t)b * H + tid])       + bf2f(hlo[(size_t)b * H + tid]);
    hb[tid + 256] = bf2f(hhi[(size_t)b * H + tid + 256]) + bf2f(hlo[(size_t)b * H + tid + 256]);
    __syncthreads();

    float acc = fc1b[tid];
    const float4* wr = (const float4*)(fc1w + (size_t)tid * H);
    const float4* hr = (const float4*)hb;
#pragma unroll 4
    for (int kk = 0; kk < H / 4; ++kk) {
        float4 wv = wr[kk], hv = hr[kk];
        acc += wv.x * hv.x + wv.y * hv.y + wv.z * hv.z + wv.w * hv.w;
    }
    z[tid] = fmaxf(acc, 0.0f);
    __syncthreads();

    if (tid < TGT) {
        float a = fc2b[tid];
        const float* w2 = fc2w + (size_t)tid * 256;
#pragma unroll 8
        for (int j = 0; j < 256; ++j) a += z[j] * w2[j];
        out[(size_t)b * TGT + tid] = a;
    }
}

extern "C" void kernel_launch(void* const* d_in, const int* in_sizes, int n_in,
                              void* d_out, int out_size, void* d_ws, size_t ws_size,
                              hipStream_t stream) {
    const float* seq  = (const float*)d_in[0];
    const float* Wih  = (const float*)d_in[1];
    const float* Whh  = (const float*)d_in[2];
    const float* bih  = (const float*)d_in[3];
    const float* bhh  = (const float*)d_in[4];
    const float* fc1w = (const float*)d_in[5];
    const float* fc1b = (const float*)d_in[6];
    const float* fc2w = (const float*)d_in[7];
    const float* fc2b = (const float*)d_in[8];
    float* out = (float*)d_out;

    char* wsb = (char*)d_ws;
    u16* wph  = (u16*)(wsb + OFF_WPH);
    u16* wpl  = (u16*)(wsb + OFF_WPL);
    u16* hhi0 = (u16*)(wsb + OFF_HHI0);
    u16* hlo0 = (u16*)(wsb + OFF_HLO0);
    u16* hhi1 = (u16*)(wsb + OFF_HHI1);
    u16* hlo1 = (u16*)(wsb + OFF_HLO1);
    int* sync = (int*)(wsb + OFF_SYNC);

    init_pack<<<512, 256, 0, stream>>>(Whh, wph, wpl);
    init_state<<<1028, 256, 0, stream>>>((unsigned*)(wsb + OFF_HHI0));

    hipFuncSetAttribute((const void*)lstm_persistent,
                        hipFuncAttributeMaxDynamicSharedMemorySize, SMEM_BYTES);

    void* args[] = {(void*)&wph, (void*)&wpl, (void*)&hhi0, (void*)&hlo0,
                    (void*)&hhi1, (void*)&hlo1, (void*)&sync, (void*)&seq,
                    (void*)&Wih, (void*)&bih, (void*)&bhh};
    hipLaunchCooperativeKernel((const void*)lstm_persistent, dim3(256), dim3(512),
                               args, SMEM_BYTES, stream);

    // T even -> final h in buffer 0
    head_kernel<<<B, 256, 0, stream>>>(hhi0, hlo0, fc1w, fc1b, fc2w, fc2b, out);
}